// Round 5
// baseline (110.300 us; speedup 1.0000x reference)
//
#include <hip/hip_runtime.h>
#include <math.h>

#define NB  4
#define NLQ 256
#define NLK 512
#define NH  256

// scale folded into projections: exp2(SC*(q+k)) = exp(2*(q+k))
#define SCALE_2LOG2E 2.885390081777927f
#define LOG2E        1.4426950408889634f

// ---------------------------------------------------------------------------
// Setup: W transposes (blocks 0..31) + per-batch mask compaction (32..35).
// ---------------------------------------------------------------------------
__global__ __launch_bounds__(256) void setup_kernel(
    const float* __restrict__ Wq, const float* __restrict__ Wk,
    const int* __restrict__ mask,
    float* __restrict__ Wtq, float* __restrict__ Wtk,
    int* __restrict__ act, int* __restrict__ nact)
{
    const int blk = blockIdx.x;
    const int t   = threadIdx.x;

    if (blk < 32) {
        // ---- transpose one 64x64 tile of Wq/Wk into Wtq/Wtk ----
        __shared__ float ts[64][65];
        const int m    = blk >> 4;               // 0: Wq, 1: Wk
        const int tile = blk & 15;
        const int h0 = (tile >> 2) * 64;
        const int c0 = (tile & 3) * 64;
        const float* W  = m ? Wk  : Wq;
        float*       Wt = m ? Wtk : Wtq;
        const int lr = t >> 4, lc = t & 15;
        #pragma unroll
        for (int i = 0; i < 4; ++i) {
            const int r = lr + 16 * i;
            const float4 d = *(const float4*)(W + (size_t)(h0 + r) * NH + c0 + lc * 4);
            ts[r][lc * 4 + 0] = d.x;
            ts[r][lc * 4 + 1] = d.y;
            ts[r][lc * 4 + 2] = d.z;
            ts[r][lc * 4 + 3] = d.w;
        }
        __syncthreads();
        #pragma unroll
        for (int i = 0; i < 4; ++i) {
            const int c = lr + 16 * i;
            float4 d;
            d.x = ts[lc * 4 + 0][c];
            d.y = ts[lc * 4 + 1][c];
            d.z = ts[lc * 4 + 2][c];
            d.w = ts[lc * 4 + 3][c];
            *(float4*)(Wt + (size_t)(c0 + c) * NH + h0 + lc * 4) = d;
        }
    } else if (blk < 32 + NB) {
        // ---- mask compaction for batch b ----
        const int b = blk - 32;
        __shared__ int wcnt[8], wpre[9];
        const int lane = t & 63, wave = t >> 6;
        const int k1 = t, k2 = t + 256;
        const int m1 = mask[b * NLK + k1];
        const int m2 = mask[b * NLK + k2];
        const unsigned long long below = (1ULL << lane) - 1ULL;
        const unsigned long long bal1 = __ballot(m1 != 0);
        const unsigned long long bal2 = __ballot(m2 != 0);
        const int r1 = __popcll(bal1 & below);
        const int r2 = __popcll(bal2 & below);
        if (lane == 0) { wcnt[wave] = __popcll(bal1); wcnt[4 + wave] = __popcll(bal2); }
        __syncthreads();
        if (t == 0) {
            int s = 0;
            #pragma unroll
            for (int w = 0; w < 8; ++w) { wpre[w] = s; s += wcnt[w]; }
            wpre[8] = s;
        }
        __syncthreads();
        const int na = wpre[8];
        if (m1) act[b * NLK + wpre[wave]     + r1] = k1;
        if (m2) act[b * NLK + wpre[4 + wave] + r2] = k2;
        if (k1 >= na) act[b * NLK + k1] = 0;     // safe tail for padded reads
        if (k2 >= na) act[b * NLK + k2] = 0;
        if (t == 0) nact[b] = na;
    }
}

// ---------------------------------------------------------------------------
// Fused projections (c-split across waves, coalesced Wt loads).
// XCD batch affinity: with round-robin block->XCD dispatch, b = idx&3 pins
// each batch's kp_ct/qp production to the XCDs that attn reads them on.
// Blocks 0..255: q rows (4/block) -> qp[b][lq][h] = exp2(scaled proj).
// Blocks 256..767: compact k slots (4/block, gathered via act) ->
//   kp_ct[b][h][j] compact-TRANSPOSED = exp2(scaled proj).
// ---------------------------------------------------------------------------
__global__ __launch_bounds__(256) void prep_kernel(
    const float* __restrict__ query, const float* __restrict__ key,
    const float* __restrict__ Wtq, const float* __restrict__ bq,
    const float* __restrict__ Wtk, const float* __restrict__ bk,
    const int* __restrict__ act, const int* __restrict__ nact,
    float* __restrict__ qp, float* __restrict__ kp_ct)
{
    const int blk  = blockIdx.x;
    const int t    = threadIdx.x;
    const int wave = t >> 6;
    const int lane = t & 63;

    __shared__ float  xs[4][NH];
    __shared__ float4 ps[4][4][64];
    __shared__ int    ridx[4];

    const float *Wt, *bias;
    int b = 0, j0 = 0, r0 = 0, na = 0;
    const bool isq = (blk < NB * NLQ / 4);

    if (isq) {
        b  = blk & 3;                            // XCD affinity
        r0 = b * NLQ + (blk >> 2) * 4;           // global q-row
        ((float4*)&xs[0][0])[t] = ((const float4*)(query + (size_t)r0 * NH))[t];
        Wt = Wtq; bias = bq;
    } else {
        const int idx = blk - 256;
        b  = idx & 3;                            // XCD affinity
        j0 = (idx >> 2) * 4;
        na = nact[b];
        if (j0 >= na) return;
        if (t < 4) ridx[t] = act[b * NLK + ((j0 + t < na) ? (j0 + t) : j0)];
        __syncthreads();
        const int r = t >> 6, c4 = t & 63;
        ((float4*)xs[r])[c4] =
            ((const float4*)(key + ((size_t)b * NLK + ridx[r]) * NH))[c4];
        Wt = Wtk; bias = bk;
    }
    __syncthreads();

    float4 acc[4];
    #pragma unroll
    for (int r = 0; r < 4; ++r) acc[r] = (float4){0.f, 0.f, 0.f, 0.f};

    const int cbase = wave * 64;
    #pragma unroll 4
    for (int cc = 0; cc < 64; ++cc) {
        const int c = cbase + cc;
        const float4 w = *(const float4*)(Wt + (size_t)c * NH + lane * 4);
        #pragma unroll
        for (int r = 0; r < 4; ++r) {
            const float xv = xs[r][c];             // LDS broadcast
            acc[r].x = fmaf(xv, w.x, acc[r].x);
            acc[r].y = fmaf(xv, w.y, acc[r].y);
            acc[r].z = fmaf(xv, w.z, acc[r].z);
            acc[r].w = fmaf(xv, w.w, acc[r].w);
        }
    }
    #pragma unroll
    for (int r = 0; r < 4; ++r) ps[wave][r][lane] = acc[r];
    __syncthreads();

    // combine: thread t -> row r = wave, h-quad l = lane
    const int r = wave, l = lane;
    const float4 p0 = ps[0][r][l], p1 = ps[1][r][l];
    const float4 p2 = ps[2][r][l], p3 = ps[3][r][l];
    const float4 bb = *(const float4*)(bias + l * 4);
    float4 o;
    o.x = (p0.x + p1.x + p2.x + p3.x + bb.x) * SCALE_2LOG2E;
    o.y = (p0.y + p1.y + p2.y + p3.y + bb.y) * SCALE_2LOG2E;
    o.z = (p0.z + p1.z + p2.z + p3.z + bb.z) * SCALE_2LOG2E;
    o.w = (p0.w + p1.w + p2.w + p3.w + bb.w) * SCALE_2LOG2E;
    // E-values: exp2 hoisted out of the attn inner loop
    o.x = __builtin_amdgcn_exp2f(o.x);
    o.y = __builtin_amdgcn_exp2f(o.y);
    o.z = __builtin_amdgcn_exp2f(o.z);
    o.w = __builtin_amdgcn_exp2f(o.w);

    if (isq) {
        *(float4*)(qp + (size_t)(r0 + r) * NH + l * 4) = o;
    } else if (j0 + r < na) {
        const int j = j0 + r;
        kp_ct[((size_t)b * NH + l * 4 + 0) * NLK + j] = o.x;
        kp_ct[((size_t)b * NH + l * 4 + 1) * NLK + j] = o.y;
        kp_ct[((size_t)b * NH + l * 4 + 2) * NLK + j] = o.z;
        kp_ct[((size_t)b * NH + l * 4 + 3) * NLK + j] = o.w;
    }
}

// ---------------------------------------------------------------------------
// Fused attn. Block = 512 threads (8 waves), FOUR q rows, grid = 256.
// 4 rows/block halves the per-block-amortized L2 streams: each kp_ct float4
// and each gathered value row now feeds 4 q-rows (was 2) -> ~98+98 MB L2.
// XCD batch affinity: b = blockIdx&3 (round-robin dispatch -> XCD serves
// one batch; working set ~1.3 MB << 4 MB L2).
// Score: wave = h-octant (32 c); lane owns slots 4l..4l+3 (+256 when na>256,
// block-uniform branch, rides the same loop). Per c: 1-2 float4 loads vs
// 16-32 rcp + 32-64 fma -> trans-pipe-bound, latency-insensitive.
// Partials [4 rows][8 oct][512 slots] = 64 KB LDS; combine: thread t = slot
// t, all 4 rows (stride-1, conflict-free). Softmax: waves 0..3 = rows 0..3.
// Output: j split across 8 waves; one float4 value load feeds 4 rows;
// 8-way LDS reduce (reusing the partial buffer).
// ---------------------------------------------------------------------------
__global__ __launch_bounds__(512) void attn_kernel(
    const float* __restrict__ qp, const float* __restrict__ kp_ct,
    const float* __restrict__ value, const int* __restrict__ mask,
    const int* __restrict__ act, const int* __restrict__ nact,
    const float* __restrict__ vvec,
    float* __restrict__ out_o, float* __restrict__ out_w)
{
    __shared__ float sc[4][NLK];
    __shared__ int   actl[NLK];
    __shared__ float eqs[4][NH];
    __shared__ float vvs[NH];
    __shared__ float4 buf4[4096];  // 64 KB: score partials [4][8][512] / out partials [4][512]

    const int blk  = blockIdx.x;
    const int b    = blk & 3;                // XCD batch affinity
    const int q0   = (blk >> 2) * 4;         // 64 q-quads per batch
    const int t    = threadIdx.x;            // 0..511
    const int lane = t & 63;
    const int wave = t >> 6;                 // 0..7

    const int na = nact[b];
    actl[t] = (t < na) ? act[b * NLK + t] : 0;
    if (t < NH) {
        eqs[0][t] = qp[(size_t)(b * NLQ + q0 + 0) * NH + t];
        eqs[1][t] = qp[(size_t)(b * NLQ + q0 + 1) * NH + t];
        eqs[2][t] = qp[(size_t)(b * NLQ + q0 + 2) * NH + t];
        eqs[3][t] = qp[(size_t)(b * NLQ + q0 + 3) * NH + t];
        vvs[t]    = vvec[t];
    }

    // zero masked out_w slots for this block's 4 rows (scatter fills actives)
    float* wrow = out_w + (size_t)(b * NLQ + q0) * NLK;
    if (!mask[b * NLK + t]) {
        wrow[t] = 0.f; wrow[NLK + t] = 0.f;
        wrow[2 * NLK + t] = 0.f; wrow[3 * NLK + t] = 0.f;
    }
    __syncthreads();                         // eqs/vvs/actl ready

    const int cb = wave * 32;                // h-octant for this wave
    const float* kb  = kp_ct + ((size_t)b * NH + cb) * NLK;
    const float* eq0 = &eqs[0][cb];
    const float* eq1 = &eqs[1][cb];
    const float* eq2 = &eqs[2][cb];
    const float* eq3 = &eqs[3][cb];
    const float* vv  = &vvs[cb];

    // ---- single score pass: 4 rows x {slots 4l, slots 256+4l} ----
    float4 a0h0 = {0,0,0,0}, a1h0 = {0,0,0,0}, a2h0 = {0,0,0,0}, a3h0 = {0,0,0,0};
    float4 a0h1 = {0,0,0,0}, a1h1 = {0,0,0,0}, a2h1 = {0,0,0,0}, a3h1 = {0,0,0,0};
    if (na > 256) {
        #pragma unroll 4
        for (int c = 0; c < 32; ++c) {
            const float4 k1 = *(const float4*)(kb + (size_t)c * NLK + 4 * lane);
            const float4 k2 = *(const float4*)(kb + (size_t)c * NLK + 256 + 4 * lane);
            const float e0 = eq0[c], e1 = eq1[c], e2 = eq2[c], e3 = eq3[c];
            const float vh = vv[c];
            a0h0.x = fmaf(vh, __builtin_amdgcn_rcpf(fmaf(e0, k1.x, 1.f)), a0h0.x);
            a0h0.y = fmaf(vh, __builtin_amdgcn_rcpf(fmaf(e0, k1.y, 1.f)), a0h0.y);
            a0h0.z = fmaf(vh, __builtin_amdgcn_rcpf(fmaf(e0, k1.z, 1.f)), a0h0.z);
            a0h0.w = fmaf(vh, __builtin_amdgcn_rcpf(fmaf(e0, k1.w, 1.f)), a0h0.w);
            a1h0.x = fmaf(vh, __builtin_amdgcn_rcpf(fmaf(e1, k1.x, 1.f)), a1h0.x);
            a1h0.y = fmaf(vh, __builtin_amdgcn_rcpf(fmaf(e1, k1.y, 1.f)), a1h0.y);
            a1h0.z = fmaf(vh, __builtin_amdgcn_rcpf(fmaf(e1, k1.z, 1.f)), a1h0.z);
            a1h0.w = fmaf(vh, __builtin_amdgcn_rcpf(fmaf(e1, k1.w, 1.f)), a1h0.w);
            a2h0.x = fmaf(vh, __builtin_amdgcn_rcpf(fmaf(e2, k1.x, 1.f)), a2h0.x);
            a2h0.y = fmaf(vh, __builtin_amdgcn_rcpf(fmaf(e2, k1.y, 1.f)), a2h0.y);
            a2h0.z = fmaf(vh, __builtin_amdgcn_rcpf(fmaf(e2, k1.z, 1.f)), a2h0.z);
            a2h0.w = fmaf(vh, __builtin_amdgcn_rcpf(fmaf(e2, k1.w, 1.f)), a2h0.w);
            a3h0.x = fmaf(vh, __builtin_amdgcn_rcpf(fmaf(e3, k1.x, 1.f)), a3h0.x);
            a3h0.y = fmaf(vh, __builtin_amdgcn_rcpf(fmaf(e3, k1.y, 1.f)), a3h0.y);
            a3h0.z = fmaf(vh, __builtin_amdgcn_rcpf(fmaf(e3, k1.z, 1.f)), a3h0.z);
            a3h0.w = fmaf(vh, __builtin_amdgcn_rcpf(fmaf(e3, k1.w, 1.f)), a3h0.w);
            a0h1.x = fmaf(vh, __builtin_amdgcn_rcpf(fmaf(e0, k2.x, 1.f)), a0h1.x);
            a0h1.y = fmaf(vh, __builtin_amdgcn_rcpf(fmaf(e0, k2.y, 1.f)), a0h1.y);
            a0h1.z = fmaf(vh, __builtin_amdgcn_rcpf(fmaf(e0, k2.z, 1.f)), a0h1.z);
            a0h1.w = fmaf(vh, __builtin_amdgcn_rcpf(fmaf(e0, k2.w, 1.f)), a0h1.w);
            a1h1.x = fmaf(vh, __builtin_amdgcn_rcpf(fmaf(e1, k2.x, 1.f)), a1h1.x);
            a1h1.y = fmaf(vh, __builtin_amdgcn_rcpf(fmaf(e1, k2.y, 1.f)), a1h1.y);
            a1h1.z = fmaf(vh, __builtin_amdgcn_rcpf(fmaf(e1, k2.z, 1.f)), a1h1.z);
            a1h1.w = fmaf(vh, __builtin_amdgcn_rcpf(fmaf(e1, k2.w, 1.f)), a1h1.w);
            a2h1.x = fmaf(vh, __builtin_amdgcn_rcpf(fmaf(e2, k2.x, 1.f)), a2h1.x);
            a2h1.y = fmaf(vh, __builtin_amdgcn_rcpf(fmaf(e2, k2.y, 1.f)), a2h1.y);
            a2h1.z = fmaf(vh, __builtin_amdgcn_rcpf(fmaf(e2, k2.z, 1.f)), a2h1.z);
            a2h1.w = fmaf(vh, __builtin_amdgcn_rcpf(fmaf(e2, k2.w, 1.f)), a2h1.w);
            a3h1.x = fmaf(vh, __builtin_amdgcn_rcpf(fmaf(e3, k2.x, 1.f)), a3h1.x);
            a3h1.y = fmaf(vh, __builtin_amdgcn_rcpf(fmaf(e3, k2.y, 1.f)), a3h1.y);
            a3h1.z = fmaf(vh, __builtin_amdgcn_rcpf(fmaf(e3, k2.z, 1.f)), a3h1.z);
            a3h1.w = fmaf(vh, __builtin_amdgcn_rcpf(fmaf(e3, k2.w, 1.f)), a3h1.w);
        }
    } else {
        #pragma unroll 4
        for (int c = 0; c < 32; ++c) {
            const float4 k1 = *(const float4*)(kb + (size_t)c * NLK + 4 * lane);
            const float e0 = eq0[c], e1 = eq1[c], e2 = eq2[c], e3 = eq3[c];
            const float vh = vv[c];
            a0h0.x = fmaf(vh, __builtin_amdgcn_rcpf(fmaf(e0, k1.x, 1.f)), a0h0.x);
            a0h0.y = fmaf(vh, __builtin_amdgcn_rcpf(fmaf(e0, k1.y, 1.f)), a0h0.y);
            a0h0.z = fmaf(vh, __builtin_amdgcn_rcpf(fmaf(e0, k1.z, 1.f)), a0h0.z);
            a0h0.w = fmaf(vh, __builtin_amdgcn_rcpf(fmaf(e0, k1.w, 1.f)), a0h0.w);
            a1h0.x = fmaf(vh, __builtin_amdgcn_rcpf(fmaf(e1, k1.x, 1.f)), a1h0.x);
            a1h0.y = fmaf(vh, __builtin_amdgcn_rcpf(fmaf(e1, k1.y, 1.f)), a1h0.y);
            a1h0.z = fmaf(vh, __builtin_amdgcn_rcpf(fmaf(e1, k1.z, 1.f)), a1h0.z);
            a1h0.w = fmaf(vh, __builtin_amdgcn_rcpf(fmaf(e1, k1.w, 1.f)), a1h0.w);
            a2h0.x = fmaf(vh, __builtin_amdgcn_rcpf(fmaf(e2, k1.x, 1.f)), a2h0.x);
            a2h0.y = fmaf(vh, __builtin_amdgcn_rcpf(fmaf(e2, k1.y, 1.f)), a2h0.y);
            a2h0.z = fmaf(vh, __builtin_amdgcn_rcpf(fmaf(e2, k1.z, 1.f)), a2h0.z);
            a2h0.w = fmaf(vh, __builtin_amdgcn_rcpf(fmaf(e2, k1.w, 1.f)), a2h0.w);
            a3h0.x = fmaf(vh, __builtin_amdgcn_rcpf(fmaf(e3, k1.x, 1.f)), a3h0.x);
            a3h0.y = fmaf(vh, __builtin_amdgcn_rcpf(fmaf(e3, k1.y, 1.f)), a3h0.y);
            a3h0.z = fmaf(vh, __builtin_amdgcn_rcpf(fmaf(e3, k1.z, 1.f)), a3h0.z);
            a3h0.w = fmaf(vh, __builtin_amdgcn_rcpf(fmaf(e3, k1.w, 1.f)), a3h0.w);
        }
    }
    // partials as float[4][8][512]: float4 idx = (row*8+wave)*128 + half*64 + lane
    buf4[(0 * 8 + wave) * 128 + lane]      = a0h0;
    buf4[(0 * 8 + wave) * 128 + 64 + lane] = a0h1;
    buf4[(1 * 8 + wave) * 128 + lane]      = a1h0;
    buf4[(1 * 8 + wave) * 128 + 64 + lane] = a1h1;
    buf4[(2 * 8 + wave) * 128 + lane]      = a2h0;
    buf4[(2 * 8 + wave) * 128 + 64 + lane] = a2h1;
    buf4[(3 * 8 + wave) * 128 + lane]      = a3h0;
    buf4[(3 * 8 + wave) * 128 + 64 + lane] = a3h1;
    __syncthreads();
    {
        // combine: thread t -> slot t, all 4 rows; 8 octant adds each
        const float* pf = (const float*)buf4;
        #pragma unroll
        for (int r = 0; r < 4; ++r) {
            float s = 0.f;
            #pragma unroll
            for (int o = 0; o < 8; ++o)
                s += pf[(r * 8 + o) * 512 + t];   // conflict-free stride-1
            sc[r][t] = (t < na) ? -2.f * s : -INFINITY;
        }
    }
    __syncthreads();

    // ---- softmax: wave r -> q row r (r = 0..3), 512 slots each ----
    if (wave < 4) {
        float* row = sc[wave];
        float vals[8];
        float m = -INFINITY;
        #pragma unroll
        for (int j8 = 0; j8 < 8; ++j8) {
            vals[j8] = row[lane + j8 * 64];
            m = fmaxf(m, vals[j8]);
        }
        #pragma unroll
        for (int s = 32; s >= 1; s >>= 1)
            m = fmaxf(m, __shfl_xor(m, s, 64));
        float sum = 0.0f;
        #pragma unroll
        for (int j8 = 0; j8 < 8; ++j8) {
            vals[j8] = __builtin_amdgcn_exp2f((vals[j8] - m) * LOG2E);
            sum += vals[j8];
        }
        #pragma unroll
        for (int s = 32; s >= 1; s >>= 1)
            sum += __shfl_xor(sum, s, 64);
        const float inv = __builtin_amdgcn_rcpf(sum);
        float* wout = out_w + (size_t)(b * NLQ + q0 + wave) * NLK;
        #pragma unroll
        for (int j8 = 0; j8 < 8; ++j8) {
            const int jj = lane + j8 * 64;
            const float w = vals[j8] * inv;
            row[jj] = w;                      // 0 for jj >= na
            if (jj < na) wout[actl[jj]] = w;  // masked slots stay 0
        }
    }
    __syncthreads();

    // ---- output: j split across 8 waves (j ≡ wave mod 8); one float4
    //      value load feeds all 4 rows; 8-way LDS reduce after ----
    {
        const int c4 = lane * 4;
        const float* vb = value + (size_t)b * NLK * NH + c4;
        float4 o0 = {0,0,0,0}, o1 = {0,0,0,0}, o2 = {0,0,0,0}, o3 = {0,0,0,0};
        #pragma unroll 4
        for (int j = wave; j < na; j += 8) {
            const float w0 = sc[0][j];        // wave-uniform LDS broadcast
            const float w1 = sc[1][j];
            const float w2 = sc[2][j];
            const float w3 = sc[3][j];
            const int   rj = actl[j];
            const float4 v4 = *(const float4*)(vb + (size_t)rj * NH);
            o0.x = fmaf(w0, v4.x, o0.x); o0.y = fmaf(w0, v4.y, o0.y);
            o0.z = fmaf(w0, v4.z, o0.z); o0.w = fmaf(w0, v4.w, o0.w);
            o1.x = fmaf(w1, v4.x, o1.x); o1.y = fmaf(w1, v4.y, o1.y);
            o1.z = fmaf(w1, v4.z, o1.z); o1.w = fmaf(w1, v4.w, o1.w);
            o2.x = fmaf(w2, v4.x, o2.x); o2.y = fmaf(w2, v4.y, o2.y);
            o2.z = fmaf(w2, v4.z, o2.z); o2.w = fmaf(w2, v4.w, o2.w);
            o3.x = fmaf(w3, v4.x, o3.x); o3.y = fmaf(w3, v4.y, o3.y);
            o3.z = fmaf(w3, v4.z, o3.z); o3.w = fmaf(w3, v4.w, o3.w);
        }
        __syncthreads();                     // sc reads done; reuse buf4
        buf4[0 * 512 + t] = o0;
        buf4[1 * 512 + t] = o1;
        buf4[2 * 512 + t] = o2;
        buf4[3 * 512 + t] = o3;
        __syncthreads();
        if (t < 256) {
            const int row = t >> 6;           // 0..3
            const int l   = t & 63;
            float4 o = buf4[row * 512 + l];
            #pragma unroll
            for (int w = 1; w < 8; ++w) {
                const float4 s = buf4[row * 512 + l + 64 * w];
                o.x += s.x; o.y += s.y; o.z += s.z; o.w += s.w;
            }
            *(float4*)(out_o + (size_t)(b * NLQ + q0 + row) * NH + l * 4) = o;
        }
    }
}

// ---------------------------------------------------------------------------
extern "C" void kernel_launch(void* const* d_in, const int* in_sizes, int n_in,
                              void* d_out, int out_size, void* d_ws, size_t ws_size,
                              hipStream_t stream) {
    const float* query = (const float*)d_in[0];
    const float* key   = (const float*)d_in[1];
    const float* value = (const float*)d_in[2];
    const int*   mask  = (const int*)  d_in[3];
    const float* Wq    = (const float*)d_in[4];
    const float* bq    = (const float*)d_in[5];
    const float* Wk    = (const float*)d_in[6];
    const float* bk    = (const float*)d_in[7];
    const float* v     = (const float*)d_in[8];
    // d_in[9] (bv) drops out of softmax -> unused

    float* out_o = (float*)d_out;                     // [4,256,256]
    float* out_w = out_o + NB * NLQ * NH;             // [4,256,512]

    float* qp    = (float*)d_ws;                      // [4,256,256] Eq
    float* kp_ct = qp + NB * NLQ * NH;                // [4,256,512] Ek compact-T
    int*   act   = (int*)(kp_ct + NB * NH * NLK);     // [4,512]
    int*   nact  = act + NB * NLK;                    // [4]

    const size_t base = (size_t)(NB * NLQ * NH) + (size_t)(NB * NH * NLK)
                      + NB * NLK + NB;                // floats+ints consumed
    float* wtq;
    if (ws_size >= (base + 2 * NH * NH) * sizeof(float)) {
        wtq = (float*)d_ws + base;                    // workspace tail
    } else {
        // park W^T in the out_w tail; attn (after prep) overwrites out_w
        wtq = out_w + (size_t)NB * NLQ * NLK - 2 * NH * NH;
    }
    float* wtk = wtq + NH * NH;

    setup_kernel<<<36, 256, 0, stream>>>(Wq, Wk, mask, wtq, wtk, act, nact);
    prep_kernel<<<NB * NLQ / 4 + NB * NLK / 4, 256, 0, stream>>>(
        query, key, wtq, bq, wtk, bk, act, nact, qp, kp_ct);
    attn_kernel<<<NB * NLQ / 4, 512, 0, stream>>>(
        qp, kp_ct, value, mask, act, nact, v, out_o, out_w);
}

// Round 6
// 108.127 us; speedup vs baseline: 1.0201x; 1.0201x over previous
//
#include <hip/hip_runtime.h>
#include <math.h>

#define NB  4
#define NLQ 256
#define NLK 512
#define NH  256

// scale folded into projections: exp2(SC*(q+k)) = exp(2*(q+k))
#define SCALE_2LOG2E 2.885390081777927f
#define LOG2E        1.4426950408889634f

// ---------------------------------------------------------------------------
// Setup: W transposes (blocks 0..31) + per-batch mask compaction (32..35).
// ---------------------------------------------------------------------------
__global__ __launch_bounds__(256) void setup_kernel(
    const float* __restrict__ Wq, const float* __restrict__ Wk,
    const int* __restrict__ mask,
    float* __restrict__ Wtq, float* __restrict__ Wtk,
    int* __restrict__ act, int* __restrict__ nact)
{
    const int blk = blockIdx.x;
    const int t   = threadIdx.x;

    if (blk < 32) {
        // ---- transpose one 64x64 tile of Wq/Wk into Wtq/Wtk ----
        __shared__ float ts[64][65];
        const int m    = blk >> 4;               // 0: Wq, 1: Wk
        const int tile = blk & 15;
        const int h0 = (tile >> 2) * 64;
        const int c0 = (tile & 3) * 64;
        const float* W  = m ? Wk  : Wq;
        float*       Wt = m ? Wtk : Wtq;
        const int lr = t >> 4, lc = t & 15;
        #pragma unroll
        for (int i = 0; i < 4; ++i) {
            const int r = lr + 16 * i;
            const float4 d = *(const float4*)(W + (size_t)(h0 + r) * NH + c0 + lc * 4);
            ts[r][lc * 4 + 0] = d.x;
            ts[r][lc * 4 + 1] = d.y;
            ts[r][lc * 4 + 2] = d.z;
            ts[r][lc * 4 + 3] = d.w;
        }
        __syncthreads();
        #pragma unroll
        for (int i = 0; i < 4; ++i) {
            const int c = lr + 16 * i;
            float4 d;
            d.x = ts[lc * 4 + 0][c];
            d.y = ts[lc * 4 + 1][c];
            d.z = ts[lc * 4 + 2][c];
            d.w = ts[lc * 4 + 3][c];
            *(float4*)(Wt + (size_t)(c0 + c) * NH + h0 + lc * 4) = d;
        }
    } else if (blk < 32 + NB) {
        // ---- mask compaction for batch b ----
        const int b = blk - 32;
        __shared__ int wcnt[8], wpre[9];
        const int lane = t & 63, wave = t >> 6;
        const int k1 = t, k2 = t + 256;
        const int m1 = mask[b * NLK + k1];
        const int m2 = mask[b * NLK + k2];
        const unsigned long long below = (1ULL << lane) - 1ULL;
        const unsigned long long bal1 = __ballot(m1 != 0);
        const unsigned long long bal2 = __ballot(m2 != 0);
        const int r1 = __popcll(bal1 & below);
        const int r2 = __popcll(bal2 & below);
        if (lane == 0) { wcnt[wave] = __popcll(bal1); wcnt[4 + wave] = __popcll(bal2); }
        __syncthreads();
        if (t == 0) {
            int s = 0;
            #pragma unroll
            for (int w = 0; w < 8; ++w) { wpre[w] = s; s += wcnt[w]; }
            wpre[8] = s;
        }
        __syncthreads();
        const int na = wpre[8];
        if (m1) act[b * NLK + wpre[wave]     + r1] = k1;
        if (m2) act[b * NLK + wpre[4 + wave] + r2] = k2;
        if (k1 >= na) act[b * NLK + k1] = 0;     // safe tail for padded reads
        if (k2 >= na) act[b * NLK + k2] = 0;
        if (t == 0) nact[b] = na;
    }
}

// ---------------------------------------------------------------------------
// Fused projections (c-split across waves, coalesced Wt loads).
// XCD batch affinity: with round-robin block->XCD dispatch, b = idx&3 pins
// each batch's kp_ct/qp production to the XCDs that attn reads them on.
// Blocks 0..255: q rows (4/block) -> qp[b][lq][h] = exp2(scaled proj).
// Blocks 256..767: compact k slots (4/block, gathered via act) ->
//   kp_ct[b][h][j] compact-TRANSPOSED = exp2(scaled proj).
// ---------------------------------------------------------------------------
__global__ __launch_bounds__(256) void prep_kernel(
    const float* __restrict__ query, const float* __restrict__ key,
    const float* __restrict__ Wtq, const float* __restrict__ bq,
    const float* __restrict__ Wtk, const float* __restrict__ bk,
    const int* __restrict__ act, const int* __restrict__ nact,
    float* __restrict__ qp, float* __restrict__ kp_ct)
{
    const int blk  = blockIdx.x;
    const int t    = threadIdx.x;
    const int wave = t >> 6;
    const int lane = t & 63;

    __shared__ float  xs[4][NH];
    __shared__ float4 ps[4][4][64];
    __shared__ int    ridx[4];

    const float *Wt, *bias;
    int b = 0, j0 = 0, r0 = 0, na = 0;
    const bool isq = (blk < NB * NLQ / 4);

    if (isq) {
        b  = blk & 3;                            // XCD affinity
        r0 = b * NLQ + (blk >> 2) * 4;           // global q-row
        ((float4*)&xs[0][0])[t] = ((const float4*)(query + (size_t)r0 * NH))[t];
        Wt = Wtq; bias = bq;
    } else {
        const int idx = blk - 256;
        b  = idx & 3;                            // XCD affinity
        j0 = (idx >> 2) * 4;
        na = nact[b];
        if (j0 >= na) return;
        if (t < 4) ridx[t] = act[b * NLK + ((j0 + t < na) ? (j0 + t) : j0)];
        __syncthreads();
        const int r = t >> 6, c4 = t & 63;
        ((float4*)xs[r])[c4] =
            ((const float4*)(key + ((size_t)b * NLK + ridx[r]) * NH))[c4];
        Wt = Wtk; bias = bk;
    }
    __syncthreads();

    float4 acc[4];
    #pragma unroll
    for (int r = 0; r < 4; ++r) acc[r] = (float4){0.f, 0.f, 0.f, 0.f};

    const int cbase = wave * 64;
    #pragma unroll 4
    for (int cc = 0; cc < 64; ++cc) {
        const int c = cbase + cc;
        const float4 w = *(const float4*)(Wt + (size_t)c * NH + lane * 4);
        #pragma unroll
        for (int r = 0; r < 4; ++r) {
            const float xv = xs[r][c];             // LDS broadcast
            acc[r].x = fmaf(xv, w.x, acc[r].x);
            acc[r].y = fmaf(xv, w.y, acc[r].y);
            acc[r].z = fmaf(xv, w.z, acc[r].z);
            acc[r].w = fmaf(xv, w.w, acc[r].w);
        }
    }
    #pragma unroll
    for (int r = 0; r < 4; ++r) ps[wave][r][lane] = acc[r];
    __syncthreads();

    // combine: thread t -> row r = wave, h-quad l = lane
    const int r = wave, l = lane;
    const float4 p0 = ps[0][r][l], p1 = ps[1][r][l];
    const float4 p2 = ps[2][r][l], p3 = ps[3][r][l];
    const float4 bb = *(const float4*)(bias + l * 4);
    float4 o;
    o.x = (p0.x + p1.x + p2.x + p3.x + bb.x) * SCALE_2LOG2E;
    o.y = (p0.y + p1.y + p2.y + p3.y + bb.y) * SCALE_2LOG2E;
    o.z = (p0.z + p1.z + p2.z + p3.z + bb.z) * SCALE_2LOG2E;
    o.w = (p0.w + p1.w + p2.w + p3.w + bb.w) * SCALE_2LOG2E;
    // E-values: exp2 hoisted out of the attn inner loop
    o.x = __builtin_amdgcn_exp2f(o.x);
    o.y = __builtin_amdgcn_exp2f(o.y);
    o.z = __builtin_amdgcn_exp2f(o.z);
    o.w = __builtin_amdgcn_exp2f(o.w);

    if (isq) {
        *(float4*)(qp + (size_t)(r0 + r) * NH + l * 4) = o;
    } else if (j0 + r < na) {
        const int j = j0 + r;
        kp_ct[((size_t)b * NH + l * 4 + 0) * NLK + j] = o.x;
        kp_ct[((size_t)b * NH + l * 4 + 1) * NLK + j] = o.y;
        kp_ct[((size_t)b * NH + l * 4 + 2) * NLK + j] = o.z;
        kp_ct[((size_t)b * NH + l * 4 + 3) * NLK + j] = o.w;
    }
}

// ---------------------------------------------------------------------------
// Fused attn. Block = 1024 threads (16 waves), FOUR q rows, grid = 256.
// 1 block/CU x 16 waves = 4 waves/SIMD (R4's occupancy) WITH R5's 4-row
// amortization (kp_ct ~128 MB, value ~98 MB L2 traffic).
// XCD batch affinity: b = blk&3; grid 256 round-robin -> XCD x serves only
// batch x%4 (blk ≡ x mod 8 -> blk&3 constant per XCD).
// Score, na>256: wave = (h-octant, slot-half); 32 c, lane owns 4 slots,
//   4 float4 accs (4 rows). Partials [4][8][512] = 64 KB.
// Score, na<=256: wave = h-sixteenth; 16 c, slots 4l. Partials [4][16][256].
// Combine: stride-1, conflict-free. Softmax: waves 0..3 = rows 0..3.
// Output: j ≡ wave mod 16; one float4 value load feeds 4 rows; 16-way LDS
// reduce (reusing the 64 KB partial buffer).
// ---------------------------------------------------------------------------
__global__ __launch_bounds__(1024) void attn_kernel(
    const float* __restrict__ qp, const float* __restrict__ kp_ct,
    const float* __restrict__ value, const int* __restrict__ mask,
    const int* __restrict__ act, const int* __restrict__ nact,
    const float* __restrict__ vvec,
    float* __restrict__ out_o, float* __restrict__ out_w)
{
    __shared__ float sc[4][NLK];
    __shared__ int   actl[NLK];
    __shared__ float eqs[4][NH];
    __shared__ float vvs[NH];
    __shared__ float4 buf4[4096];  // 64 KB: score partials / out partials [4][1024]

    const int blk  = blockIdx.x;
    const int b    = blk & 3;                // XCD batch affinity
    const int q0   = (blk >> 2) * 4;         // 64 q-quads per batch
    const int t    = threadIdx.x;            // 0..1023
    const int lane = t & 63;
    const int wave = t >> 6;                 // 0..15

    const int na = nact[b];
    if (t < NLK) actl[t] = (t < na) ? act[b * NLK + t] : 0;
    if (t < NH) {
        eqs[0][t] = qp[(size_t)(b * NLQ + q0 + 0) * NH + t];
        eqs[1][t] = qp[(size_t)(b * NLQ + q0 + 1) * NH + t];
        eqs[2][t] = qp[(size_t)(b * NLQ + q0 + 2) * NH + t];
        eqs[3][t] = qp[(size_t)(b * NLQ + q0 + 3) * NH + t];
        vvs[t]    = vvec[t];
    }

    // zero masked out_w slots for this block's 4 rows (scatter fills actives)
    if (t < NLK) {
        float* wrow = out_w + (size_t)(b * NLQ + q0) * NLK;
        if (!mask[b * NLK + t]) {
            wrow[t] = 0.f; wrow[NLK + t] = 0.f;
            wrow[2 * NLK + t] = 0.f; wrow[3 * NLK + t] = 0.f;
        }
    }
    __syncthreads();                         // eqs/vvs/actl ready

    // ---- single score pass ----
    if (na > 256) {
        const int oct  = wave & 7;           // h-octant
        const int half = wave >> 3;          // slot half
        const int cb   = oct * 32;
        const int s0   = half * 256 + 4 * lane;
        const float* kb  = kp_ct + ((size_t)b * NH + cb) * NLK;
        const float* eq0 = &eqs[0][cb];
        const float* eq1 = &eqs[1][cb];
        const float* eq2 = &eqs[2][cb];
        const float* eq3 = &eqs[3][cb];
        const float* vv  = &vvs[cb];
        float4 a0 = {0,0,0,0}, a1 = {0,0,0,0}, a2 = {0,0,0,0}, a3 = {0,0,0,0};
        #pragma unroll 4
        for (int c = 0; c < 32; ++c) {
            const float4 k1 = *(const float4*)(kb + (size_t)c * NLK + s0);
            const float e0 = eq0[c], e1 = eq1[c], e2 = eq2[c], e3 = eq3[c];
            const float vh = vv[c];
            a0.x = fmaf(vh, __builtin_amdgcn_rcpf(fmaf(e0, k1.x, 1.f)), a0.x);
            a0.y = fmaf(vh, __builtin_amdgcn_rcpf(fmaf(e0, k1.y, 1.f)), a0.y);
            a0.z = fmaf(vh, __builtin_amdgcn_rcpf(fmaf(e0, k1.z, 1.f)), a0.z);
            a0.w = fmaf(vh, __builtin_amdgcn_rcpf(fmaf(e0, k1.w, 1.f)), a0.w);
            a1.x = fmaf(vh, __builtin_amdgcn_rcpf(fmaf(e1, k1.x, 1.f)), a1.x);
            a1.y = fmaf(vh, __builtin_amdgcn_rcpf(fmaf(e1, k1.y, 1.f)), a1.y);
            a1.z = fmaf(vh, __builtin_amdgcn_rcpf(fmaf(e1, k1.z, 1.f)), a1.z);
            a1.w = fmaf(vh, __builtin_amdgcn_rcpf(fmaf(e1, k1.w, 1.f)), a1.w);
            a2.x = fmaf(vh, __builtin_amdgcn_rcpf(fmaf(e2, k1.x, 1.f)), a2.x);
            a2.y = fmaf(vh, __builtin_amdgcn_rcpf(fmaf(e2, k1.y, 1.f)), a2.y);
            a2.z = fmaf(vh, __builtin_amdgcn_rcpf(fmaf(e2, k1.z, 1.f)), a2.z);
            a2.w = fmaf(vh, __builtin_amdgcn_rcpf(fmaf(e2, k1.w, 1.f)), a2.w);
            a3.x = fmaf(vh, __builtin_amdgcn_rcpf(fmaf(e3, k1.x, 1.f)), a3.x);
            a3.y = fmaf(vh, __builtin_amdgcn_rcpf(fmaf(e3, k1.y, 1.f)), a3.y);
            a3.z = fmaf(vh, __builtin_amdgcn_rcpf(fmaf(e3, k1.z, 1.f)), a3.z);
            a3.w = fmaf(vh, __builtin_amdgcn_rcpf(fmaf(e3, k1.w, 1.f)), a3.w);
        }
        // float[4][8][512]: float4 idx = (r*8+oct)*128 + half*64 + lane
        buf4[(0 * 8 + oct) * 128 + half * 64 + lane] = a0;
        buf4[(1 * 8 + oct) * 128 + half * 64 + lane] = a1;
        buf4[(2 * 8 + oct) * 128 + half * 64 + lane] = a2;
        buf4[(3 * 8 + oct) * 128 + half * 64 + lane] = a3;
    } else {
        const int cb = wave * 16;            // h-sixteenth
        const int s0 = 4 * lane;
        const float* kb  = kp_ct + ((size_t)b * NH + cb) * NLK;
        const float* eq0 = &eqs[0][cb];
        const float* eq1 = &eqs[1][cb];
        const float* eq2 = &eqs[2][cb];
        const float* eq3 = &eqs[3][cb];
        const float* vv  = &vvs[cb];
        float4 a0 = {0,0,0,0}, a1 = {0,0,0,0}, a2 = {0,0,0,0}, a3 = {0,0,0,0};
        #pragma unroll 4
        for (int c = 0; c < 16; ++c) {
            const float4 k1 = *(const float4*)(kb + (size_t)c * NLK + s0);
            const float e0 = eq0[c], e1 = eq1[c], e2 = eq2[c], e3 = eq3[c];
            const float vh = vv[c];
            a0.x = fmaf(vh, __builtin_amdgcn_rcpf(fmaf(e0, k1.x, 1.f)), a0.x);
            a0.y = fmaf(vh, __builtin_amdgcn_rcpf(fmaf(e0, k1.y, 1.f)), a0.y);
            a0.z = fmaf(vh, __builtin_amdgcn_rcpf(fmaf(e0, k1.z, 1.f)), a0.z);
            a0.w = fmaf(vh, __builtin_amdgcn_rcpf(fmaf(e0, k1.w, 1.f)), a0.w);
            a1.x = fmaf(vh, __builtin_amdgcn_rcpf(fmaf(e1, k1.x, 1.f)), a1.x);
            a1.y = fmaf(vh, __builtin_amdgcn_rcpf(fmaf(e1, k1.y, 1.f)), a1.y);
            a1.z = fmaf(vh, __builtin_amdgcn_rcpf(fmaf(e1, k1.z, 1.f)), a1.z);
            a1.w = fmaf(vh, __builtin_amdgcn_rcpf(fmaf(e1, k1.w, 1.f)), a1.w);
            a2.x = fmaf(vh, __builtin_amdgcn_rcpf(fmaf(e2, k1.x, 1.f)), a2.x);
            a2.y = fmaf(vh, __builtin_amdgcn_rcpf(fmaf(e2, k1.y, 1.f)), a2.y);
            a2.z = fmaf(vh, __builtin_amdgcn_rcpf(fmaf(e2, k1.z, 1.f)), a2.z);
            a2.w = fmaf(vh, __builtin_amdgcn_rcpf(fmaf(e2, k1.w, 1.f)), a2.w);
            a3.x = fmaf(vh, __builtin_amdgcn_rcpf(fmaf(e3, k1.x, 1.f)), a3.x);
            a3.y = fmaf(vh, __builtin_amdgcn_rcpf(fmaf(e3, k1.y, 1.f)), a3.y);
            a3.z = fmaf(vh, __builtin_amdgcn_rcpf(fmaf(e3, k1.z, 1.f)), a3.z);
            a3.w = fmaf(vh, __builtin_amdgcn_rcpf(fmaf(e3, k1.w, 1.f)), a3.w);
        }
        // float[4][16][256]: float4 idx = (r*16+wave)*64 + lane
        buf4[(0 * 16 + wave) * 64 + lane] = a0;
        buf4[(1 * 16 + wave) * 64 + lane] = a1;
        buf4[(2 * 16 + wave) * 64 + lane] = a2;
        buf4[(3 * 16 + wave) * 64 + lane] = a3;
    }
    __syncthreads();

    // ---- combine partials -> sc (stride-1, conflict-free) ----
    if (na > 256) {
        const int s  = t & 511;
        const int rb = (t >> 9) * 2;         // rows {0,1} or {2,3}
        const float* pf = (const float*)buf4;
        #pragma unroll
        for (int ri = 0; ri < 2; ++ri) {
            const int r = rb + ri;
            float sum = 0.f;
            #pragma unroll
            for (int o = 0; o < 8; ++o) sum += pf[(r * 8 + o) * 512 + s];
            sc[r][s] = (s < na) ? -2.f * sum : -INFINITY;
        }
    } else {
        const int s = t & 255;
        const int r = t >> 8;                // 0..3
        const float* pf = (const float*)buf4;
        float sum = 0.f;
        #pragma unroll
        for (int o = 0; o < 16; ++o) sum += pf[(r * 16 + o) * 256 + s];
        sc[r][s]       = (s < na) ? -2.f * sum : -INFINITY;
        sc[r][s + 256] = -INFINITY;
    }
    __syncthreads();

    // ---- softmax: wave r -> q row r (r = 0..3), 512 slots each ----
    if (wave < 4) {
        float* row = sc[wave];
        float vals[8];
        float m = -INFINITY;
        #pragma unroll
        for (int j8 = 0; j8 < 8; ++j8) {
            vals[j8] = row[lane + j8 * 64];
            m = fmaxf(m, vals[j8]);
        }
        #pragma unroll
        for (int s = 32; s >= 1; s >>= 1)
            m = fmaxf(m, __shfl_xor(m, s, 64));
        float sum = 0.0f;
        #pragma unroll
        for (int j8 = 0; j8 < 8; ++j8) {
            vals[j8] = __builtin_amdgcn_exp2f((vals[j8] - m) * LOG2E);
            sum += vals[j8];
        }
        #pragma unroll
        for (int s = 32; s >= 1; s >>= 1)
            sum += __shfl_xor(sum, s, 64);
        const float inv = __builtin_amdgcn_rcpf(sum);
        float* wout = out_w + (size_t)(b * NLQ + q0 + wave) * NLK;
        #pragma unroll
        for (int j8 = 0; j8 < 8; ++j8) {
            const int jj = lane + j8 * 64;
            const float w = vals[j8] * inv;
            row[jj] = w;                      // 0 for jj >= na
            if (jj < na) wout[actl[jj]] = w;  // masked slots stay 0
        }
    }
    __syncthreads();

    // ---- output: j ≡ wave (mod 16); one float4 value load feeds 4 rows;
    //      16-way LDS reduce (reusing buf4) ----
    {
        const int c4 = lane * 4;
        const float* vb = value + (size_t)b * NLK * NH + c4;
        float4 o0 = {0,0,0,0}, o1 = {0,0,0,0}, o2 = {0,0,0,0}, o3 = {0,0,0,0};
        #pragma unroll 4
        for (int j = wave; j < na; j += 16) {
            const float w0 = sc[0][j];        // wave-uniform LDS broadcast
            const float w1 = sc[1][j];
            const float w2 = sc[2][j];
            const float w3 = sc[3][j];
            const int   rj = actl[j];
            const float4 v4 = *(const float4*)(vb + (size_t)rj * NH);
            o0.x = fmaf(w0, v4.x, o0.x); o0.y = fmaf(w0, v4.y, o0.y);
            o0.z = fmaf(w0, v4.z, o0.z); o0.w = fmaf(w0, v4.w, o0.w);
            o1.x = fmaf(w1, v4.x, o1.x); o1.y = fmaf(w1, v4.y, o1.y);
            o1.z = fmaf(w1, v4.z, o1.z); o1.w = fmaf(w1, v4.w, o1.w);
            o2.x = fmaf(w2, v4.x, o2.x); o2.y = fmaf(w2, v4.y, o2.y);
            o2.z = fmaf(w2, v4.z, o2.z); o2.w = fmaf(w2, v4.w, o2.w);
            o3.x = fmaf(w3, v4.x, o3.x); o3.y = fmaf(w3, v4.y, o3.y);
            o3.z = fmaf(w3, v4.z, o3.z); o3.w = fmaf(w3, v4.w, o3.w);
        }
        __syncthreads();                     // sc reads done; reuse buf4
        buf4[0 * 1024 + t] = o0;
        buf4[1 * 1024 + t] = o1;
        buf4[2 * 1024 + t] = o2;
        buf4[3 * 1024 + t] = o3;
        __syncthreads();
        if (t < 256) {
            const int row = t >> 6;           // 0..3
            const int l   = t & 63;
            float4 o = buf4[row * 1024 + l];
            #pragma unroll
            for (int w = 1; w < 16; ++w) {
                const float4 s = buf4[row * 1024 + l + 64 * w];
                o.x += s.x; o.y += s.y; o.z += s.z; o.w += s.w;
            }
            *(float4*)(out_o + (size_t)(b * NLQ + q0 + row) * NH + l * 4) = o;
        }
    }
}

// ---------------------------------------------------------------------------
extern "C" void kernel_launch(void* const* d_in, const int* in_sizes, int n_in,
                              void* d_out, int out_size, void* d_ws, size_t ws_size,
                              hipStream_t stream) {
    const float* query = (const float*)d_in[0];
    const float* key   = (const float*)d_in[1];
    const float* value = (const float*)d_in[2];
    const int*   mask  = (const int*)  d_in[3];
    const float* Wq    = (const float*)d_in[4];
    const float* bq    = (const float*)d_in[5];
    const float* Wk    = (const float*)d_in[6];
    const float* bk    = (const float*)d_in[7];
    const float* v     = (const float*)d_in[8];
    // d_in[9] (bv) drops out of softmax -> unused

    float* out_o = (float*)d_out;                     // [4,256,256]
    float* out_w = out_o + NB * NLQ * NH;             // [4,256,512]

    float* qp    = (float*)d_ws;                      // [4,256,256] Eq
    float* kp_ct = qp + NB * NLQ * NH;                // [4,256,512] Ek compact-T
    int*   act   = (int*)(kp_ct + NB * NH * NLK);     // [4,512]
    int*   nact  = act + NB * NLK;                    // [4]

    const size_t base = (size_t)(NB * NLQ * NH) + (size_t)(NB * NH * NLK)
                      + NB * NLK + NB;                // floats+ints consumed
    float* wtq;
    if (ws_size >= (base + 2 * NH * NH) * sizeof(float)) {
        wtq = (float*)d_ws + base;                    // workspace tail
    } else {
        // park W^T in the out_w tail; attn (after prep) overwrites out_w
        wtq = out_w + (size_t)NB * NLQ * NLK - 2 * NH * NH;
    }
    float* wtk = wtq + NH * NH;

    setup_kernel<<<36, 256, 0, stream>>>(Wq, Wk, mask, wtq, wtk, act, nact);
    prep_kernel<<<NB * NLQ / 4 + NB * NLK / 4, 256, 0, stream>>>(
        query, key, wtq, bq, wtk, bk, act, nact, qp, kp_ct);
    attn_kernel<<<NB * NLQ / 4, 1024, 0, stream>>>(
        qp, kp_ct, value, mask, act, nact, v, out_o, out_w);
}